// Round 15
// baseline (54.889 us; speedup 1.0000x reference)
//
#include <hip/hip_runtime.h>

#define NT 64             // one wave per block, 64 particles
#define NSTEP 50
#define AW 36             // A: entries 0..23  -> 36 packed dwords (LDS, P1)
#define BW 39             // B: entries 24..49 -> 39 packed dwords (regs, P2)
#define RSTR 39           // LDS row stride = max(AW, BW); region reused A->B

__device__ __forceinline__ void lorenz(float x, float y, float z,
                                       float S, float R, float Bb,
                                       float c0, float c1, float c2,
                                       float& dx, float& dy, float& dz) {
    dx = S * (y - x) + c0;
    dy = x * (R - z) - y + c1;
    dz = x * y - Bb * z + c2;
}

// pack two f32 -> two bf16 (round-half-up) in one dword; lo in low half
__device__ __forceinline__ unsigned int bpack(float lo, float hi) {
    unsigned int a = (__builtin_bit_cast(unsigned int, lo) + 0x8000u) >> 16;
    unsigned int b = (__builtin_bit_cast(unsigned int, hi) + 0x8000u) & 0xFFFF0000u;
    return a | b;
}
__device__ __forceinline__ float bunpack_lo(unsigned int w) {
    return __builtin_bit_cast(float, w << 16);
}
__device__ __forceinline__ float bunpack_hi(unsigned int w) {
    return __builtin_bit_cast(float, w & 0xFFFF0000u);
}

__device__ __forceinline__ float tanh_fast(float x) {
    float e = __expf(2.0f * x);
    float r = __builtin_amdgcn_rcpf(e + 1.0f);
    return __builtin_fmaf(-2.0f, r, 1.0f);
}
__device__ __forceinline__ float sigmoid_fast(float x) {
    float e = __expf(-x);
    return __builtin_amdgcn_rcpf(1.0f + e);
}

// LDS-only fence: orders ds ops (cross-lane visibility within the wave)
// WITHOUT draining global stores — preserves fire-and-forget store overlap.
__device__ __forceinline__ void lds_fence() {
    asm volatile("s_waitcnt lgkmcnt(0)" ::: "memory");
}

__global__ __launch_bounds__(NT, 4) void chaotic_embed_kernel(
    const float* __restrict__ features,
    const float* __restrict__ W1,  const float* __restrict__ b1,
    const float* __restrict__ W2,  const float* __restrict__ b2,
    const float* __restrict__ Wc1, const float* __restrict__ bc1,
    const float* __restrict__ Wc2, const float* __restrict__ bc2,
    const float* __restrict__ Wp1, const float* __restrict__ bp1,
    const float* __restrict__ Wp2, const float* __restrict__ bp2,
    float* __restrict__ out)
{
    __shared__ unsigned int region[NT * RSTR];   // 9984 B -> 16 blocks/CU

    const int lane = threadIdx.x;
    const long pbase = (long)blockIdx.x * NT;

    const float4 f4 = ((const float4*)features)[pbase + lane];
    const float fv[4] = {f4.x, f4.y, f4.z, f4.w};

    // ---- MLPs: compile-time weight indices -> uniform s_load, SGPR operands
    float h1[16];
    #pragma unroll
    for (int j = 0; j < 16; ++j) {
        float a = b1[j];
        #pragma unroll
        for (int i = 0; i < 4; ++i) a = __builtin_fmaf(fv[i], W1[i * 16 + j], a);
        h1[j] = tanh_fast(a);
    }
    float init[3];
    #pragma unroll
    for (int c = 0; c < 3; ++c) {
        float a = b2[c];
        #pragma unroll
        for (int j = 0; j < 16; ++j) a = __builtin_fmaf(h1[j], W2[j * 3 + c], a);
        init[c] = 2.0f * tanh_fast(a);
    }
    float hc[8];
    #pragma unroll
    for (int j = 0; j < 8; ++j) {
        float a = bc1[j];
        #pragma unroll
        for (int i = 0; i < 4; ++i) a = __builtin_fmaf(fv[i], Wc1[i * 8 + j], a);
        hc[j] = tanh_fast(a);
    }
    float coup[3];
    #pragma unroll
    for (int c = 0; c < 3; ++c) {
        float a = bc2[c];
        #pragma unroll
        for (int j = 0; j < 8; ++j) a = __builtin_fmaf(hc[j], Wc2[j * 3 + c], a);
        coup[c] = tanh_fast(a);
    }
    float hp[8];
    #pragma unroll
    for (int j = 0; j < 8; ++j) {
        float a = bp1[j];
        #pragma unroll
        for (int i = 0; i < 4; ++i) a = __builtin_fmaf(fv[i], Wp1[i * 8 + j], a);
        hp[j] = fmaxf(a, 0.0f);
    }
    float sc[3];
    #pragma unroll
    for (int c = 0; c < 3; ++c) {
        float a = bp2[c];
        #pragma unroll
        for (int j = 0; j < 8; ++j) a = __builtin_fmaf(hp[j], Wp2[j * 3 + c], a);
        sc[c] = sigmoid_fast(a);
    }
    const float S  = 10.0f * (0.5f + sc[0]);
    const float R  = 28.0f * (0.5f + sc[1]);
    const float Bb = (8.0f / 3.0f) * (0.5f + sc[2]);
    const float c0 = coup[0], c1 = coup[1], c2 = coup[2];
    const float H = 0.01f, HH = 0.5f * 0.01f, H6 = 0.01f / 6.0f;

    float sx = init[0], sy = init[1], sz = init[2];
    float px, py, pz;

    auto step = [&]() {
        float k1x, k1y, k1z, k2x, k2y, k2z, k3x, k3y, k3z, k4x, k4y, k4z;
        lorenz(sx, sy, sz, S, R, Bb, c0, c1, c2, k1x, k1y, k1z);
        lorenz(sx + HH * k1x, sy + HH * k1y, sz + HH * k1z,
               S, R, Bb, c0, c1, c2, k2x, k2y, k2z);
        lorenz(sx + HH * k2x, sy + HH * k2y, sz + HH * k2z,
               S, R, Bb, c0, c1, c2, k3x, k3y, k3z);
        lorenz(sx + H * k3x, sy + H * k3y, sz + H * k3z,
               S, R, Bb, c0, c1, c2, k4x, k4y, k4z);
        sx += H6 * (k1x + 2.0f * k2x + 2.0f * k3x + k4x);
        sy += H6 * (k1y + 2.0f * k2y + 2.0f * k3y + k4y);
        sz += H6 * (k1z + 2.0f * k2z + 2.0f * k3z + k4z);
    };

    unsigned int* row = region + lane * RSTR;   // stride 39 (odd): 2-way = free

    // ======== P1: steps 1..23, entries 0..23 -> LDS dwords 0..35 ========
    {
        px = sx; py = sy; pz = sz;    // entry 0 = init
        step();                        // entry 1
        row[0] = bpack(px, py);
        row[1] = bpack(pz, sx);
        row[2] = bpack(sy, sz);
    }
    #pragma unroll
    for (int g = 1; g < 12; ++g) {
        step();                        // entry 2g
        px = sx; py = sy; pz = sz;
        step();                        // entry 2g+1
        row[3 * g + 0] = bpack(px, py);
        row[3 * g + 1] = bpack(pz, sx);
        row[3 * g + 2] = bpack(sy, sz);
    }

    lds_fence();   // A image visible to all lanes of this wave

    float* __restrict__ outW = out + pbase * 150;   // block f32 base (64B-aligned)

    // ======== P2: steps 24..49; B entries -> regs; trickle-flush A ========
    // A flush: 36 iterations; lane covers image dword i=64k+lane;
    // pp = i/36, slot = i%36 (magic mul), lds = pp*39+slot, out = pp*150+2*slot.
    unsigned int rb[39];
    constexpr int fend[14] = {0,3,6,9,11,14,17,20,22,25,28,31,33,36};
    #pragma unroll
    for (int g = 0; g < 13; ++g) {
        step();                        // entry 24+2g
        px = sx; py = sy; pz = sz;
        step();                        // entry 25+2g
        rb[3 * g + 0] = bpack(px, py);
        rb[3 * g + 1] = bpack(pz, sx);
        rb[3 * g + 2] = bpack(sy, sz);
        #pragma unroll
        for (int k = fend[g]; k < fend[g + 1]; ++k) {
            const int i  = 64 * k + lane;
            const int pp = i / 36;
            const int sl = i - 36 * pp;
            const unsigned int v = region[pp * RSTR + sl];
            float2 o;
            o.x = bunpack_lo(v);
            o.y = bunpack_hi(v);
            *(float2*)(outW + pp * 150 + 2 * sl) = o;   // 8B-aligned
        }
    }

    lds_fence();   // A ds_reads retired -> region reusable (stores keep draining)

    // ======== P3: dump B regs -> LDS, bulk-flush B (entries 24..49) ========
    #pragma unroll
    for (int s = 0; s < 39; ++s) row[s] = rb[s];
    lds_fence();   // B image visible

    #pragma unroll 4
    for (int k = 0; k < 39; ++k) {
        const int i  = 64 * k + lane;     // B image IS linear (stride 39, 39 used)
        const int pp = i / 39;
        const int sl = i - 39 * pp;
        const unsigned int v = region[i];
        float2 o;
        o.x = bunpack_lo(v);
        o.y = bunpack_hi(v);
        *(float2*)(outW + pp * 150 + 72 + 2 * sl) = o;
    }
}

extern "C" void kernel_launch(void* const* d_in, const int* in_sizes, int n_in,
                              void* d_out, int out_size, void* d_ws, size_t ws_size,
                              hipStream_t stream) {
    const float* features = (const float*)d_in[0];
    const float* W1  = (const float*)d_in[1];
    const float* b1  = (const float*)d_in[2];
    const float* W2  = (const float*)d_in[3];
    const float* b2  = (const float*)d_in[4];
    const float* Wc1 = (const float*)d_in[5];
    const float* bc1 = (const float*)d_in[6];
    const float* Wc2 = (const float*)d_in[7];
    const float* bc2 = (const float*)d_in[8];
    const float* Wp1 = (const float*)d_in[9];
    const float* bp1 = (const float*)d_in[10];
    const float* Wp2 = (const float*)d_in[11];
    const float* bp2 = (const float*)d_in[12];
    float* out = (float*)d_out;

    const int B = in_sizes[0] / 4;          // 262144
    const int grid = B / NT;                // 4096 one-wave blocks, 16/CU

    chaotic_embed_kernel<<<grid, NT, 0, stream>>>(
        features, W1, b1, W2, b2, Wc1, bc1, Wc2, bc2,
        Wp1, bp1, Wp2, bp2, out);
}